// Round 7
// baseline (10323.167 us; speedup 1.0000x reference)
//
#include <hip/hip_runtime.h>
#include <hip/hip_bf16.h>

#define BB 64
#define TT 512
#define CC 512
#define HH 512

using bf16 = __hip_bfloat16;
typedef short s16x8 __attribute__((ext_vector_type(8)));
typedef float f32x4 __attribute__((ext_vector_type(4)));

static __device__ __forceinline__ s16x8 ld8(const bf16* p) {
  return *reinterpret_cast<const s16x8*>(p);
}

static __device__ __forceinline__ float sigm(float x) {
  return 1.f / (1.f + __expf(-x));
}
static __device__ __forceinline__ float tanh_fast(float x) {
  x = fminf(fmaxf(x, -20.f), 20.f);
  float e = __expf(2.f * x);
  return (e - 1.f) / (e + 1.f);
}

__global__ void cast_w_kernel(const float* __restrict__ s, bf16* __restrict__ d, int n) {
  int stride = gridDim.x * blockDim.x;
  for (int i = blockIdx.x * blockDim.x + threadIdx.x; i < n; i += stride)
    d[i] = __float2bfloat16(s[i]);
}

__global__ void zero_ws_kernel(unsigned* __restrict__ p, int nwords) {
  int i = blockIdx.x * blockDim.x + threadIdx.x;
  if (i < nwords) p[i] = 0u;
}

// x (B,C,T) f32 -> xT (T,B,C) bf16   (time-major: per-tick slab contiguous 64KB)
__global__ void transpose_x_kernel(const float* __restrict__ x, bf16* __restrict__ xT) {
  __shared__ float tile[32][33];
  int b = blockIdx.z;
  int t0 = blockIdx.x * 32, c0 = blockIdx.y * 32;
  const float* xb = x + (size_t)b * CC * TT;
  for (int i = threadIdx.y; i < 32; i += 8)
    tile[i][threadIdx.x] = xb[(size_t)(c0 + i) * TT + t0 + threadIdx.x];
  __syncthreads();
  for (int i = threadIdx.y; i < 32; i += 8)
    xT[(size_t)(t0 + i) * (BB * CC) + (size_t)b * CC + c0 + threadIdx.x] =
        __float2bfloat16(tile[threadIdx.x][i]);
}

// Persistent LAYER-FUSED pipelined LSTM. 64 WGs x 256 thr (4 waves).
// WG: beta = bx>>5 (batch half, independent gang), ch-group = bx&31 (16 channels of BOTH
// layers). Wave g = gate g. Tick u (0..512): compute h1(u) (u<512) and h2(u-1) (u>=1).
// Both dependencies (h1(u-1), h2(u-2)) were published at tick u-1 -> ONE poll, ONE flag
// per tick. h1(u-1) A-fragments are shared by the two dependent GEMMs. out[] scatter
// stores are issued AFTER the flag store (off the critical drain path).
// Sync: per-producer flag STORES (no RMW), relaxed agent scope; h slabs are write-once
// history buffers stored via agent-scope write-through atomics, consumed by plain loads.
__global__ __launch_bounds__(256, 1) void lstm_persist_kernel(
    const bf16* __restrict__ Wi1, const bf16* __restrict__ Wh1,
    const float* __restrict__ bih1, const float* __restrict__ bhh1,
    const bf16* __restrict__ Wi2, const bf16* __restrict__ Wh2,
    const float* __restrict__ bih2, const float* __restrict__ bhh2,
    const bf16* __restrict__ xT,   // (T, B, C) bf16
    bf16* __restrict__ h1h,        // (T, B, H) bf16 history
    bf16* __restrict__ h2h,        // (T, B, H) bf16 history
    float* __restrict__ out,       // (B, H, T) f32
    unsigned* __restrict__ flags)  // [2][32] u32, zeroed
{
  const int tid = threadIdx.x;
  const int g = tid >> 6, l = tid & 63;
  const int lr = l & 15, lk = (l >> 4) * 8;
  const int beta = blockIdx.x >> 5;
  const int ch0 = (blockIdx.x & 31) * 16;
  const int b0 = beta * 32;

  // Weight row pointers: gate g, rows ch0+lr, k-contig 512 each.
  const bf16* rA1 = Wi1 + (size_t)(g * 512 + ch0 + lr) * 512 + lk;  // x(u)    -> gates1
  const bf16* rB1 = Wh1 + (size_t)(g * 512 + ch0 + lr) * 512 + lk;  // h1(u-1) -> gates1
  const bf16* rA2 = Wi2 + (size_t)(g * 512 + ch0 + lr) * 512 + lk;  // h1(u-1) -> gates2
  const bf16* rB2 = Wh2 + (size_t)(g * 512 + ch0 + lr) * 512 + lk;  // h2(u-2) -> gates2

  // Cell ownership: thread -> batch mloc = tid>>3 (of 32), channel pair q2 = (tid&7)*2.
  const int mloc = tid >> 3;
  const int m = b0 + mloc;
  const int q2 = (tid & 7) * 2;
  float bs1[4][2], bs2[4][2];
#pragma unroll
  for (int gg = 0; gg < 4; ++gg)
#pragma unroll
    for (int k = 0; k < 2; ++k) {
      bs1[gg][k] = bih1[gg * 512 + ch0 + q2 + k] + bhh1[gg * 512 + ch0 + q2 + k];
      bs2[gg][k] = bih2[gg * 512 + ch0 + q2 + k] + bhh2[gg * 512 + ch0 + q2 + k];
    }
  float c1[2] = {0.f, 0.f}, c2[2] = {0.f, 0.f};

  unsigned* fl = flags + (size_t)beta * 32;
  const unsigned* myfw = fl + (l & 31);

  __shared__ float Gs1[4][32][17], Gs2[4][32][17];

  for (int u = 0; u <= TT; ++u) {
    f32x4 acc1[2] = {};
    f32x4 acc2[2] = {};

    // ---- x-GEMM: no cross-WG dependency; runs before the poll ----
    if (u < TT) {
      const bf16* A = xT + (size_t)u * (BB * CC) + (size_t)b0 * 512;
#pragma unroll
      for (int kq = 0; kq < 16; ++kq) {
        s16x8 w = ld8(rA1 + kq * 32);
#pragma unroll
        for (int mi = 0; mi < 2; ++mi) {
          s16x8 a = ld8(A + (size_t)(mi * 16 + lr) * 512 + kq * 32 + lk);
          acc1[mi] = __builtin_amdgcn_mfma_f32_16x16x32_bf16(a, w, acc1[mi], 0, 0, 0);
        }
      }
    }

    if (u >= 1) {
      // ---- single poll: gang flags >= u means h1(u-1) and h2(u-2) are published ----
      const unsigned tgt = (unsigned)u;
      for (;;) {
        unsigned v = __hip_atomic_load(myfw, __ATOMIC_RELAXED, __HIP_MEMORY_SCOPE_AGENT);
        if (!__any((int)(v < tgt))) break;
        __builtin_amdgcn_s_sleep(1);
      }

      // ---- dependent GEMMs; h1(u-1) fragments shared by both layers ----
      const bf16* A1 = h1h + (size_t)(u - 1) * (BB * HH) + (size_t)b0 * 512;
      const bf16* A2 = h2h + (size_t)(u - 2) * (BB * HH) + (size_t)b0 * 512;  // u>=2 only
      if (u < TT) {
#pragma unroll
        for (int kq = 0; kq < 16; ++kq) {
          s16x8 wb1 = ld8(rB1 + kq * 32);
          s16x8 wa2 = ld8(rA2 + kq * 32);
#pragma unroll
          for (int mi = 0; mi < 2; ++mi) {
            s16x8 a = ld8(A1 + (size_t)(mi * 16 + lr) * 512 + kq * 32 + lk);
            acc1[mi] = __builtin_amdgcn_mfma_f32_16x16x32_bf16(a, wb1, acc1[mi], 0, 0, 0);
            acc2[mi] = __builtin_amdgcn_mfma_f32_16x16x32_bf16(a, wa2, acc2[mi], 0, 0, 0);
          }
        }
      } else {
#pragma unroll
        for (int kq = 0; kq < 16; ++kq) {
          s16x8 wa2 = ld8(rA2 + kq * 32);
#pragma unroll
          for (int mi = 0; mi < 2; ++mi) {
            s16x8 a = ld8(A1 + (size_t)(mi * 16 + lr) * 512 + kq * 32 + lk);
            acc2[mi] = __builtin_amdgcn_mfma_f32_16x16x32_bf16(a, wa2, acc2[mi], 0, 0, 0);
          }
        }
      }
      if (u >= 2) {
#pragma unroll
        for (int kq = 0; kq < 16; ++kq) {
          s16x8 wb2 = ld8(rB2 + kq * 32);
#pragma unroll
          for (int mi = 0; mi < 2; ++mi) {
            s16x8 a = ld8(A2 + (size_t)(mi * 16 + lr) * 512 + kq * 32 + lk);
            acc2[mi] = __builtin_amdgcn_mfma_f32_16x16x32_bf16(a, wb2, acc2[mi], 0, 0, 0);
          }
        }
      }
    }

    // ---- exchange gate tiles across waves ----
    if (u < TT)
#pragma unroll
      for (int mi = 0; mi < 2; ++mi)
#pragma unroll
        for (int r = 0; r < 4; ++r)
          Gs1[g][mi * 16 + (l >> 4) * 4 + r][lr] = acc1[mi][r];
    if (u >= 1)
#pragma unroll
      for (int mi = 0; mi < 2; ++mi)
#pragma unroll
        for (int r = 0; r < 4; ++r)
          Gs2[g][mi * 16 + (l >> 4) * 4 + r][lr] = acc2[mi][r];
    __syncthreads();

    // ---- cell updates (c in registers), h stores (agent write-through) ----
    float hv2[2];
    if (u < TT) {
      bf16* hout = h1h + (size_t)u * (BB * HH);
      union { ushort us[2]; unsigned v; } pk;
#pragma unroll
      for (int k = 0; k < 2; ++k) {
        int cc = q2 + k;
        float gi = sigm(Gs1[0][mloc][cc] + bs1[0][k]);
        float gf = sigm(Gs1[1][mloc][cc] + bs1[1][k]);
        float gg = tanh_fast(Gs1[2][mloc][cc] + bs1[2][k]);
        float go = sigm(Gs1[3][mloc][cc] + bs1[3][k]);
        float cv = gf * c1[k] + gi * gg;
        c1[k] = cv;
        float hvf = go * tanh_fast(cv);
        bf16 hb = __float2bfloat16(hvf);
        pk.us[k] = *reinterpret_cast<ushort*>(&hb);
      }
      __hip_atomic_store((unsigned*)(hout + (size_t)m * 512 + ch0 + q2), pk.v,
                         __ATOMIC_RELAXED, __HIP_MEMORY_SCOPE_AGENT);
    }
    if (u >= 1) {
      bf16* hout = h2h + (size_t)(u - 1) * (BB * HH);
      union { ushort us[2]; unsigned v; } pk;
#pragma unroll
      for (int k = 0; k < 2; ++k) {
        int cc = q2 + k;
        float gi = sigm(Gs2[0][mloc][cc] + bs2[0][k]);
        float gf = sigm(Gs2[1][mloc][cc] + bs2[1][k]);
        float gg = tanh_fast(Gs2[2][mloc][cc] + bs2[2][k]);
        float go = sigm(Gs2[3][mloc][cc] + bs2[3][k]);
        float cv = gf * c2[k] + gi * gg;
        c2[k] = cv;
        hv2[k] = go * tanh_fast(cv);
        bf16 hb = __float2bfloat16(hv2[k]);
        pk.us[k] = *reinterpret_cast<ushort*>(&hb);
      }
      __hip_atomic_store((unsigned*)(hout + (size_t)m * 512 + ch0 + q2), pk.v,
                         __ATOMIC_RELAXED, __HIP_MEMORY_SCOPE_AGENT);
    }

    // ---- drain h stores, then ONE flag store; out[] scatter goes AFTER the flag ----
    asm volatile("s_waitcnt vmcnt(0)" ::: "memory");
    __syncthreads();
    if (tid == 0)
      __hip_atomic_store(fl + (blockIdx.x & 31), (unsigned)(u + 1),
                         __ATOMIC_RELAXED, __HIP_MEMORY_SCOPE_AGENT);
    if (u >= 1) {
      const int t = u - 1;
#pragma unroll
      for (int k = 0; k < 2; ++k)
        out[((size_t)m * 512 + ch0 + q2 + k) * 512 + t] = hv2[k];
    }
  }
}

extern "C" void kernel_launch(void* const* d_in, const int* in_sizes, int n_in,
                              void* d_out, int out_size, void* d_ws, size_t ws_size,
                              hipStream_t stream) {
  const float* x    = (const float*)d_in[0];
  const float* Wih1 = (const float*)d_in[1];
  const float* Whh1 = (const float*)d_in[2];
  const float* bih1 = (const float*)d_in[3];
  const float* bhh1 = (const float*)d_in[4];
  const float* Wih2 = (const float*)d_in[5];
  const float* Whh2 = (const float*)d_in[6];
  const float* bih2 = (const float*)d_in[7];
  const float* bhh2 = (const float*)d_in[8];
  float* out = (float*)d_out;

  // Workspace layout (~104 MB + 256B flags)
  const size_t MB = 1ull << 20;
  char* p = (char*)d_ws;
  bf16*     xT    = (bf16*)(p);               // 32MB (T,B,C)
  bf16*     h1h   = (bf16*)(p + 32 * MB);     // 32MB (T,B,H) history
  bf16*     h2h   = (bf16*)(p + 64 * MB);     // 32MB (T,B,H) history
  bf16*     W1i   = (bf16*)(p + 96 * MB);     // 2MB each
  bf16*     W1h   = (bf16*)(p + 98 * MB);
  bf16*     W2i   = (bf16*)(p + 100 * MB);
  bf16*     W2h   = (bf16*)(p + 102 * MB);
  unsigned* flags = (unsigned*)(p + 104 * MB);  // [2][32] u32 = 256B
  if (ws_size < 104 * MB + 256) return;

  const int NW = 4 * HH * CC;  // 1048576 elements per weight matrix
  cast_w_kernel<<<1024, 256, 0, stream>>>(Wih1, W1i, NW);
  cast_w_kernel<<<1024, 256, 0, stream>>>(Whh1, W1h, NW);
  cast_w_kernel<<<1024, 256, 0, stream>>>(Wih2, W2i, NW);
  cast_w_kernel<<<1024, 256, 0, stream>>>(Whh2, W2h, NW);
  transpose_x_kernel<<<dim3(16, 16, 64), dim3(32, 8), 0, stream>>>(x, xT);
  zero_ws_kernel<<<1, 64, 0, stream>>>(flags, 64);

  lstm_persist_kernel<<<64, 256, 0, stream>>>(W1i, W1h, bih1, bhh1,
                                              W2i, W2h, bih2, bhh2,
                                              xT, h1h, h2h, out, flags);
}

// Round 10
// 4814.226 us; speedup vs baseline: 2.1443x; 2.1443x over previous
//
#include <hip/hip_runtime.h>
#include <hip/hip_bf16.h>

#define BB 64
#define TT 512
#define CC 512
#define HH 512

using bf16 = __hip_bfloat16;
typedef short s16x8 __attribute__((ext_vector_type(8)));
typedef float f32x4 __attribute__((ext_vector_type(4)));

static __device__ __forceinline__ s16x8 ld8(const bf16* p) {
  return *reinterpret_cast<const s16x8*>(p);
}

static __device__ __forceinline__ float sigm(float x) {
  return 1.f / (1.f + __expf(-x));
}
static __device__ __forceinline__ float tanh_fast(float x) {
  x = fminf(fmaxf(x, -20.f), 20.f);
  float e = __expf(2.f * x);
  return (e - 1.f) / (e + 1.f);
}

__global__ void cast_w_kernel(const float* __restrict__ s, bf16* __restrict__ d, int n) {
  int stride = gridDim.x * blockDim.x;
  for (int i = blockIdx.x * blockDim.x + threadIdx.x; i < n; i += stride)
    d[i] = __float2bfloat16(s[i]);
}

__global__ void zero_ws_kernel(unsigned* __restrict__ p, int nwords) {
  int i = blockIdx.x * blockDim.x + threadIdx.x;
  if (i < nwords) p[i] = 0u;
}

// x (B,C,T) f32 -> xT (T,B,C) bf16   (time-major: per-tick slab contiguous 64KB)
__global__ void transpose_x_kernel(const float* __restrict__ x, bf16* __restrict__ xT) {
  __shared__ float tile[32][33];
  int b = blockIdx.z;
  int t0 = blockIdx.x * 32, c0 = blockIdx.y * 32;
  const float* xb = x + (size_t)b * CC * TT;
  for (int i = threadIdx.y; i < 32; i += 8)
    tile[i][threadIdx.x] = xb[(size_t)(c0 + i) * TT + t0 + threadIdx.x];
  __syncthreads();
  for (int i = threadIdx.y; i < 32; i += 8)
    xT[(size_t)(t0 + i) * (BB * CC) + (size_t)b * CC + c0 + threadIdx.x] =
        __float2bfloat16(tile[threadIdx.x][i]);
}

// Persistent pipelined 2-layer LSTM (round-5 structure) + REGISTER-PINNED weights.
// 128 WGs x 256 thr (4 waves). WG: layer = bx>>6, beta = (bx>>5)&1, ch-group = bx&31
// (16 channels). Wave g = gate g, M = 32 batches, K = 1024 = [in | h_prev].
// Weights are loaded ONCE via inline-asm global_load_dwordx4 ("=v" outputs cannot be
// rematerialized -> 128 VGPRs stay live across all 512 ticks; per-tick memory traffic
// is only the two 32KB A-slabs). out[] uses non-temporal stores so the 128MB output
// doesn't evict weights/xT/h from L2/L3 (L3-thrash fix: live set now < 256MB).
// Sync: per-producer flag STORES (no RMW), relaxed agent scope; h slabs write-once via
// agent-scope write-through atomics; consumers plain loads; all-wave coalesced poll.
__global__ __launch_bounds__(256, 1) void lstm_persist_kernel(
    const bf16* __restrict__ Wi1, const bf16* __restrict__ Wh1,
    const float* __restrict__ bih1, const float* __restrict__ bhh1,
    const bf16* __restrict__ Wi2, const bf16* __restrict__ Wh2,
    const float* __restrict__ bih2, const float* __restrict__ bhh2,
    const bf16* __restrict__ xT,   // (T, B, C) bf16
    bf16* __restrict__ h1h,        // (T, B, H) bf16 history
    bf16* __restrict__ h2h,        // (T, B, H) bf16 history
    float* __restrict__ out,       // (B, H, T) f32
    unsigned* __restrict__ flags)  // [2][2][32] u32, zeroed
{
  const int tid = threadIdx.x;
  const int g = tid >> 6, l = tid & 63;
  const int lr = l & 15, lk = (l >> 4) * 8;
  const int layer = blockIdx.x >> 6;
  const int beta = (blockIdx.x >> 5) & 1;
  const int ch0 = (blockIdx.x & 31) * 16;
  const int b0 = beta * 32;

  const bf16* WA = layer ? Wi2 : Wi1;   // multiplies A0 (x(t) or h1(t))
  const bf16* WB = layer ? Wh2 : Wh1;   // multiplies A1 (h_prev(t-1))
  const float* bi = layer ? bih2 : bih1;
  const float* bh = layer ? bhh2 : bhh1;

  // ---- PINNED weight fragments: 16 rows (gate g, ch0..+15) x K=512, two streams ----
  // asm-produced values can't be rematerialized; they live in 128 VGPRs for the whole
  // kernel. vmcnt(0)+sched_barrier(0) fences uses (rule #18).
  s16x8 wa[16], wb[16];
  {
    const bf16* rowA = WA + (size_t)(g * 512 + ch0 + lr) * 512 + lk;
    const bf16* rowB = WB + (size_t)(g * 512 + ch0 + lr) * 512 + lk;
#pragma unroll
    for (int kq = 0; kq < 16; ++kq) {
      asm volatile("global_load_dwordx4 %0, %1, off"
                   : "=v"(wa[kq]) : "v"(rowA + kq * 32));
      asm volatile("global_load_dwordx4 %0, %1, off"
                   : "=v"(wb[kq]) : "v"(rowB + kq * 32));
    }
    asm volatile("s_waitcnt vmcnt(0)" ::: "memory");
    __builtin_amdgcn_sched_barrier(0);
  }

  // Cell ownership: thread -> batch m = b0 + (tid>>3), channel pair q2 = (tid&7)*2.
  const int mloc = tid >> 3;
  const int m = b0 + mloc;
  const int q2 = (tid & 7) * 2;
  float bs[4][2];
#pragma unroll
  for (int gg = 0; gg < 4; ++gg)
#pragma unroll
    for (int k = 0; k < 2; ++k)
      bs[gg][k] = bi[gg * 512 + ch0 + q2 + k] + bh[gg * 512 + ch0 + q2 + k];
  float cst[2] = {0.f, 0.f};

  unsigned* fl_own = flags + ((size_t)layer * 2 + beta) * 32;  // this WG's gang
  unsigned* fl_src = flags + (size_t)beta * 32;                // layer-1 gang, same beta

  // Per-lane poll word. Layer 0: all lanes poll own gang (>= t: h1(t-1) done).
  // Layer 1: lanes 0..31 poll source gang (>= t+1: h1(t) ready), lanes 32..63 poll own
  // gang (>= t: h2(t-1) ready).
  const unsigned* myfw;
  int tgt_off;
  if (layer == 0)      { myfw = fl_own + (l & 31); tgt_off = 0; }
  else if (l < 32)     { myfw = fl_src + l;        tgt_off = 1; }
  else                 { myfw = fl_own + (l - 32); tgt_off = 0; }

  __shared__ float Gs[4][32][17];

  for (int t = 0; t < TT; ++t) {
    f32x4 acc[2] = {};

    auto gemm = [&](const bf16* A, const s16x8* w) {
#pragma unroll
      for (int kq = 0; kq < 16; ++kq) {
#pragma unroll
        for (int mi = 0; mi < 2; ++mi) {
          s16x8 a = ld8(A + (size_t)(b0 + mi * 16 + lr) * 512 + kq * 32 + lk);
          acc[mi] = __builtin_amdgcn_mfma_f32_16x16x32_bf16(a, w[kq], acc[mi], 0, 0, 0);
        }
      }
    };
    auto poll = [&]() {
      const unsigned tgt = (unsigned)(t + tgt_off);
      for (;;) {
        unsigned v = __hip_atomic_load(myfw, __ATOMIC_RELAXED, __HIP_MEMORY_SCOPE_AGENT);
        if (!__any((int)(v < tgt))) break;
        __builtin_amdgcn_s_sleep(1);
      }
    };

    if (layer == 0) {
      // x-GEMM has no cross-WG dependency: compute it BEFORE waiting on h1(t-1).
      gemm(xT + (size_t)t * (BB * CC), wa);
      poll();
      if (t > 0) gemm(h1h + (size_t)(t - 1) * (BB * HH), wb);
    } else {
      poll();
      gemm(h1h + (size_t)t * (BB * HH), wa);
      if (t > 0) gemm(h2h + (size_t)(t - 1) * (BB * HH), wb);
    }

    // Exchange gate tiles across waves: wave g holds gate g for 32 b x 16 ch.
#pragma unroll
    for (int mi = 0; mi < 2; ++mi)
#pragma unroll
      for (int r = 0; r < 4; ++r)
        Gs[g][mi * 16 + (l >> 4) * 4 + r][lr] = acc[mi][r];
    __syncthreads();

    // Cell update: 2 channels of one batch per thread; c-state in registers.
    bf16* hout = (layer ? h2h : h1h) + (size_t)t * (BB * HH);
    float hv[2];
    union { ushort us[2]; unsigned v; } pk;
#pragma unroll
    for (int k = 0; k < 2; ++k) {
      int cc = q2 + k;
      float gi = sigm(Gs[0][mloc][cc] + bs[0][k]);
      float gf = sigm(Gs[1][mloc][cc] + bs[1][k]);
      float gg = tanh_fast(Gs[2][mloc][cc] + bs[2][k]);
      float go = sigm(Gs[3][mloc][cc] + bs[3][k]);
      float cv = gf * cst[k] + gi * gg;
      cst[k] = cv;
      hv[k] = go * tanh_fast(cv);
      bf16 hb = __float2bfloat16(hv[k]);
      pk.us[k] = *reinterpret_cast<ushort*>(&hb);
    }
    // h square: 4B agent-scope write-through store (lands at coherence point).
    __hip_atomic_store((unsigned*)(hout + (size_t)m * 512 + ch0 + q2), pk.v,
                       __ATOMIC_RELAXED, __HIP_MEMORY_SCOPE_AGENT);

    // Drain the h store, sync WG, ONE flag store (no RMW).
    asm volatile("s_waitcnt vmcnt(0)" ::: "memory");
    __syncthreads();
    if (tid == 0)
      __hip_atomic_store(fl_own + (blockIdx.x & 31), (unsigned)(t + 1),
                         __ATOMIC_RELAXED, __HIP_MEMORY_SCOPE_AGENT);

    // out[] scatter AFTER the flag (off the critical path), non-temporal so the 128MB
    // output never evicts weights/xT/h from L2/L3.
    if (layer) {
#pragma unroll
      for (int k = 0; k < 2; ++k)
        __builtin_nontemporal_store(hv[k], &out[((size_t)m * 512 + ch0 + q2 + k) * 512 + t]);
    }
  }
}

extern "C" void kernel_launch(void* const* d_in, const int* in_sizes, int n_in,
                              void* d_out, int out_size, void* d_ws, size_t ws_size,
                              hipStream_t stream) {
  const float* x    = (const float*)d_in[0];
  const float* Wih1 = (const float*)d_in[1];
  const float* Whh1 = (const float*)d_in[2];
  const float* bih1 = (const float*)d_in[3];
  const float* bhh1 = (const float*)d_in[4];
  const float* Wih2 = (const float*)d_in[5];
  const float* Whh2 = (const float*)d_in[6];
  const float* bih2 = (const float*)d_in[7];
  const float* bhh2 = (const float*)d_in[8];
  float* out = (float*)d_out;

  // Workspace layout (~104 MB + 512B flags)
  const size_t MB = 1ull << 20;
  char* p = (char*)d_ws;
  bf16*     xT    = (bf16*)(p);               // 32MB (T,B,C)
  bf16*     h1h   = (bf16*)(p + 32 * MB);     // 32MB (T,B,H) history
  bf16*     h2h   = (bf16*)(p + 64 * MB);     // 32MB (T,B,H) history
  bf16*     W1i   = (bf16*)(p + 96 * MB);     // 2MB each
  bf16*     W1h   = (bf16*)(p + 98 * MB);
  bf16*     W2i   = (bf16*)(p + 100 * MB);
  bf16*     W2h   = (bf16*)(p + 102 * MB);
  unsigned* flags = (unsigned*)(p + 104 * MB);  // [2][2][32] u32 = 512B
  if (ws_size < 104 * MB + 512) return;

  const int NW = 4 * HH * CC;  // 1048576 elements per weight matrix
  cast_w_kernel<<<1024, 256, 0, stream>>>(Wih1, W1i, NW);
  cast_w_kernel<<<1024, 256, 0, stream>>>(Whh1, W1h, NW);
  cast_w_kernel<<<1024, 256, 0, stream>>>(Wih2, W2i, NW);
  cast_w_kernel<<<1024, 256, 0, stream>>>(Whh2, W2h, NW);
  transpose_x_kernel<<<dim3(16, 16, 64), dim3(32, 8), 0, stream>>>(x, xT);
  zero_ws_kernel<<<1, 128, 0, stream>>>(flags, 128);

  lstm_persist_kernel<<<128, 256, 0, stream>>>(W1i, W1h, bih1, bhh1,
                                               W2i, W2h, bih2, bhh2,
                                               xT, h1h, h2h, out, flags);
}